// Round 12
// baseline (568.869 us; speedup 1.0000x reference)
//
#include <hip/hip_runtime.h>

// log2(1e-7): frac < 1e-7  <=>  log2(frac) < this
#define LOG2_EPS_CLAMP -23.2534966f

__device__ __forceinline__ float flog2(float x) { return __builtin_amdgcn_logf(x); }

// 16 waves/block (1024 thr); wave s owns exactly ONE i (i = s) for the
// block's 64 neurons (one per lane). Per-thread state: the 32 raw bins of
// its i-row (f0/f1[16]) -- the m12 partial IS this row, so no accumulator
// arrays. Single HBM pass; phase 2 is registers + LDS only.
__global__ __launch_bounds__(1024) void pid_kernel(const float* __restrict__ p,
                                                   float* __restrict__ out,
                                                   const int N) {
    __shared__ float m12buf[32][64];     // full m12 (8 KB), LDS atomics
    __shared__ float ibuf[3][16][64];    // I1/I2/I4 per-wave partials (12 KB)

    const int tid = threadIdx.x;
    const int g   = tid & 63;            // neuron offset in block
    const int s   = tid >> 6;            // wave id 0..15 == owned i
    const int n   = blockIdx.x * 64 + g;
    const bool active = (n < N);

    const float* __restrict__ qi = p + n + (size_t)(s * 32) * (size_t)N;

    // ---- issue all 32 coalesced loads first (256B segments) ----
    float f0[16], f1[16];
    if (active) {
        #pragma unroll
        for (int j = 0; j < 16; ++j) {
            f0[j] = qi[(size_t)(2 * j) * (size_t)N];
            f1[j] = qi[(size_t)(2 * j + 1) * (size_t)N];
        }
    } else {
        #pragma unroll
        for (int j = 0; j < 16; ++j) { f0[j] = 0.f; f1[j] = 0.f; }
    }

    // zero the atomic target while loads are in flight
    ((float*)m12buf)[tid] = 0.f;
    ((float*)m12buf)[1024 + tid] = 0.f;
    __syncthreads();

    // own-i m02 slice
    float a0 = 0.f, a1 = 0.f;
    #pragma unroll
    for (int j = 0; j < 16; ++j) { a0 += f0[j]; a1 += f1[j]; }

    // m12 reduction: this thread's partial IS its f-row
    #pragma unroll
    for (int j = 0; j < 16; ++j) {
        atomicAdd(&m12buf[2 * j][g],     f0[j]);
        atomicAdd(&m12buf[2 * j + 1][g], f1[j]);
    }
    __syncthreads();

    // pin f (and a) in registers across the barrier -- forbid re-load
    #pragma unroll
    for (int j = 0; j < 16; ++j) asm volatile("" : "+v"(f0[j]), "+v"(f1[j]));
    asm volatile("" : "+v"(a0), "+v"(a1));

    // P2 marginal from LDS (2-way bank alias: free)
    float P20 = 0.f, P21 = 0.f;
    #pragma unroll
    for (int j = 0; j < 16; ++j) { P20 += m12buf[2 * j][g]; P21 += m12buf[2 * j + 1][g]; }
    const float LP20 = flog2(P20);
    const float LP21 = flog2(P21);

    // ---- phase 2: I1 ({0}{1}), I4 ({01}), I2 for own i ----
    float I1 = 0.f, I4 = 0.f;
    const float m0i = a0 + a1;
    #pragma unroll
    for (int j = 0; j < 16; ++j) {
        const float w0 = m12buf[2 * j][g];
        const float w1 = m12buf[2 * j + 1][g];
        const float fa = f0[j], fb = f1[j];
        const float p01 = fa + fb;
        const float u1  = m0i + (w0 + w1) - p01;
        const float Lu1  = flog2(u1);
        const float Lp01 = flog2(p01);
        // k = 0
        {
            const float num = a0 + w0 - fa;
            float l1 = flog2(num) - Lu1 - LP20;
            l1 = (l1 < LOG2_EPS_CLAMP) ? 0.f : l1;
            I1 = fmaf(fa, l1, I1);
            float l4 = flog2(fa) - Lp01 - LP20;
            l4 = (l4 < LOG2_EPS_CLAMP) ? 0.f : l4;
            I4 = fmaf(fa, l4, I4);
        }
        // k = 1
        {
            const float num = a1 + w1 - fb;
            float l1 = flog2(num) - Lu1 - LP21;
            l1 = (l1 < LOG2_EPS_CLAMP) ? 0.f : l1;
            I1 = fmaf(fb, l1, I1);
            float l4 = flog2(fb) - Lp01 - LP21;
            l4 = (l4 < LOG2_EPS_CLAMP) ? 0.f : l4;
            I4 = fmaf(fb, l4, I4);
        }
    }
    // I2 contribution of own i
    float I2;
    {
        const float L0 = flog2(m0i);
        float la = flog2(a0) - L0 - LP20;
        la = (la < LOG2_EPS_CLAMP) ? 0.f : la;
        float lb = flog2(a1) - L0 - LP21;
        lb = (lb < LOG2_EPS_CLAMP) ? 0.f : lb;
        I2 = a0 * la + a1 * lb;
    }

    ibuf[0][s][g] = I1;
    ibuf[1][s][g] = I2;
    ibuf[2][s][g] = I4;
    __syncthreads();

    if (s == 0 && active) {
        float r1 = 0.f, r2 = 0.f, r4 = 0.f;
        #pragma unroll
        for (int w = 0; w < 16; ++w) {
            r1 += ibuf[0][w][g];
            r2 += ibuf[1][w][g];
            r4 += ibuf[2][w][g];
        }

        // I3 = I(X1;Y) from full m12
        float I3 = 0.f;
        #pragma unroll
        for (int j = 0; j < 16; ++j) {
            const float w0 = m12buf[2 * j][g];
            const float w1 = m12buf[2 * j + 1][g];
            const float L1 = flog2(w0 + w1);
            float la = flog2(w0) - L1 - LP20;
            la = (la < LOG2_EPS_CLAMP) ? 0.f : la;
            I3 = fmaf(w0, la, I3);
            float lb = flog2(w1) - L1 - LP21;
            lb = (lb < LOG2_EPS_CLAMP) ? 0.f : lb;
            I3 = fmaf(w1, lb, I3);
        }
        const float H = -(P20 * flog2(P20 + 1e-10f) + P21 * flog2(P21 + 1e-10f));

        out[0 * N + n] = r1;
        out[1 * N + n] = r2 - r1;
        out[2 * N + n] = I3 - r1;
        out[3 * N + n] = r1 - r2 - I3 + r4;
        out[4 * N + n] = H - r4;
    }
}

extern "C" void kernel_launch(void* const* d_in, const int* in_sizes, int n_in,
                              void* d_out, int out_size, void* d_ws, size_t ws_size,
                              hipStream_t stream) {
    const float* p = (const float*)d_in[0];
    float* out = (float*)d_out;
    const int N = in_sizes[0] / 512;          // (16*16*2) bins per neuron
    const int blocks = (N + 63) / 64;         // 64 neurons per 1024-thread block
    pid_kernel<<<blocks, 1024, 0, stream>>>(p, out, N);
}